// Round 14
// baseline (80.942 us; speedup 1.0000x reference)
//
#include <hip/hip_runtime.h>

#define NATOMS 10000
#define KNB 32
#define FD 128
#define NRBF 300
#define STEPC (30.0f / 299.0f)      // linspace(0.1,30.1,300) step
#define INVSTEP (299.0f / 30.0f)
#define TROWS 256                   // filter table rows, d in [0,32), h = 1/8

typedef short short8 __attribute__((ext_vector_type(8)));
typedef float f32x4 __attribute__((ext_vector_type(4)));
typedef unsigned int u32x4 __attribute__((ext_vector_type(4)));

__device__ __forceinline__ unsigned short f2bf_rne(float f) {
    unsigned int u = __float_as_uint(f);
    u = (u + 0x7fffu + ((u >> 16) & 1u)) >> 16;
    return (unsigned short)u;
}

// pack two floats -> one u32 of 2 bf16 (round-half-up), lo in bits[15:0]
__device__ __forceinline__ unsigned int pack_bf2(float hi, float lo) {
    return __builtin_amdgcn_perm(__float_as_uint(hi) + 0x8000u,
                                 __float_as_uint(lo) + 0x8000u, 0x07060302u);
}

__device__ __forceinline__ unsigned short f2bf_rhu(float f) {
    return (unsigned short)((__float_as_uint(f) + 0x8000u) >> 16);
}

// exact-ish shifted softplus (2 trans) — unbounded input
__device__ __forceinline__ float ssp_fast(float x) {
    float t = __builtin_amdgcn_exp2f(x * 1.44269504f);
    float l = __builtin_amdgcn_logf(1.0f + t);
    return 0.69314718056f * (l - 1.0f);
}

// even-series shifted softplus, valid |x| <= ~2.5, NO transcendentals.
__device__ __forceinline__ float ssp_poly(float x) {
    float u = x * x;
    float p = fmaf(u, 2.1356923e-6f, -2.6351976e-5f);
    p = fmaf(u, p, 3.2552083e-4f);
    p = fmaf(u, p, -5.2083333e-3f);
    p = fmaf(u, p, 0.125f);
    return fmaf(0.5f, x, u * p);
}

// async global->LDS, 16B per lane; lds dest = wave-uniform base + lane*16
__device__ __forceinline__ void gload_lds16(const void* g, void* l) {
    __builtin_amdgcn_global_load_lds(
        (const __attribute__((address_space(1))) unsigned int*)g,
        (__attribute__((address_space(3))) unsigned int*)l, 16, 0, 0);
}

// 8 consecutive RBF values for distance d, packed bf16 (recurrence, 2 exp2)
__device__ __forceinline__ short8 rbf_row8(float d, float cg) {
    float t = d - cg;
    t = fminf(3.5f, fmaxf(-3.5f, t));
    float r = __builtin_amdgcn_exp2f(-14.4269504f * t * t);
    float q = __builtin_amdgcn_exp2f((28.8539008f * STEPC) * t
                                     - (14.4269504f * STEPC * STEPC));
    const float QRATIO = 0.81763172f;                 // 2^(-28.8539008*STEPC^2)
    u32x4 p;
#pragma unroll
    for (int jj = 0; jj < 4; ++jj) {
        float v0 = r; r *= q; q *= QRATIO;
        float v1 = r; r *= q; q *= QRATIO;
        p[jj] = pack_bf2(v1, v0);
    }
    return __builtin_bit_cast(short8, p);
}

// b-frag built on the fly from f32 row-major W: shorts j=0..7 = W[k0+j][c]
__device__ __forceinline__ short8 load_bfrag_f32(const float* __restrict__ W,
                                                 int k0, int c) {
    u32x4 p;
#pragma unroll
    for (int jj = 0; jj < 4; ++jj) {
        int ka = k0 + 2 * jj;
        p[jj] = pack_bf2(W[(ka + 1) * FD + c], W[ka * FD + c]);
    }
    return __builtin_bit_cast(short8, p);
}

// guarded variant for W_cf1 (rows >= kmax read as 0)
__device__ __forceinline__ short8 load_bfrag_f32_g(const float* __restrict__ W,
                                                   int k0, int c, int kmax) {
    u32x4 p;
#pragma unroll
    for (int jj = 0; jj < 4; ++jj) {
        int ka = k0 + 2 * jj;
        float va = (ka < kmax) ? W[ka * FD + c] : 0.f;
        float vb = (ka + 1 < kmax) ? W[(ka + 1) * FD + c] : 0.f;
        p[jj] = pack_bf2(vb, va);
    }
    return __builtin_bit_cast(short8, p);
}

// K1, three roles by blockIdx:
//  [0,313):  pre role — preP = pack(atomic @ W_pre + b), 32 rows/block,
//            4 waves col-split (wave (r,c) = 16 rows x 64 cols), B-frags
//            built on the fly from f32 W_pre.
//  [313,315): table role — 256-row filter table T (d = r/8,
//            F = ssp(ssp(rbf@W1)@W2)); entry (r, j) u32 = bf16 pair cols
//            (32*(j&3)+(j>>2), +16); B-frags on the fly from f32 W_cf1/W_cf2.
//  [315,317): pack role — W_post1/W_post2 -> bf16 [4][4][128][8] at wp.
__global__ __launch_bounds__(256) void pre_table_pack(
    const float* __restrict__ X, const float* __restrict__ Wpre,
    const float* __restrict__ bias, unsigned int* __restrict__ preP,
    const float* __restrict__ Wcf1, const float* __restrict__ Wcf2,
    unsigned int* __restrict__ T, const float* __restrict__ Wpost1,
    const float* __restrict__ Wpost2, unsigned short* __restrict__ wp) {
    __shared__ unsigned short A2[128][132];   // table role only
    const int tid = threadIdx.x;
    const int w = tid >> 6, lane = tid & 63, g = lane >> 4, c16 = lane & 15;

    if (blockIdx.x < 313) {
        // ---- pre role ----
        const int r0b = blockIdx.x * 32;
        const int r = w >> 1, c = w & 1;
        int row = r0b + r * 16 + c16;
        if (row >= NATOMS) row = 0;

        f32x4 acc[4];
#pragma unroll
        for (int b = 0; b < 4; ++b) acc[b] = (f32x4){0.f, 0.f, 0.f, 0.f};

#pragma unroll
        for (int kc = 0; kc < 4; ++kc) {
            const float* p0 = X + (size_t)row * FD + kc * 32 + g * 8;
            float4 xa = *(const float4*)p0, xb = *(const float4*)(p0 + 4);
            u32x4 pa;
            pa[0] = pack_bf2(xa.y, xa.x); pa[1] = pack_bf2(xa.w, xa.z);
            pa[2] = pack_bf2(xb.y, xb.x); pa[3] = pack_bf2(xb.w, xb.z);
            short8 a0 = __builtin_bit_cast(short8, pa);
            int k0 = kc * 32 + g * 8;
#pragma unroll
            for (int nb = 0; nb < 4; ++nb) {
                short8 b = load_bfrag_f32(Wpre, k0, (c * 4 + nb) * 16 + c16);
                acc[nb] = __builtin_amdgcn_mfma_f32_16x16x32_bf16(a0, b, acc[nb], 0, 0, 0);
            }
        }

        float bv[4];
#pragma unroll
        for (int nb = 0; nb < 4; ++nb) bv[nb] = bias[(c * 4 + nb) * 16 + c16];
#pragma unroll
        for (int q = 0; q < 4; ++q) {
            int orow = r0b + r * 16 + 4 * g + q;
            if (orow < NATOMS) {
#pragma unroll
                for (int pp = 0; pp < 2; ++pp) {
                    float v0 = acc[2 * pp][q] + bv[2 * pp];
                    float v1 = acc[2 * pp + 1][q] + bv[2 * pp + 1];
                    preP[orow * 64 + c16 * 4 + c * 2 + pp] = pack_bf2(v1, v0);
                }
            }
        }
        return;
    }

    if (blockIdx.x >= 315) {
        // ---- pack role: W_post{1,2} -> wp ----
        const int sel = blockIdx.x - 315;
        const float* W = sel ? Wpost2 : Wpost1;
        unsigned short* o = wp + sel * 16384;
        for (int t2 = tid; t2 < 16384; t2 += 256) {
            int j = t2 & 7, cc = (t2 >> 3) & 127, gg = (t2 >> 10) & 3, kc = t2 >> 12;
            int k = kc * 32 + gg * 8 + j;
            o[t2] = f2bf_rne(W[k * FD + cc]);
        }
        return;
    }

    // ---- table role: 32 rows/wave, 128 rows/block, d = r/8 ----
    const int rbase = (int)(blockIdx.x - 313) * 128 + w * 32;
    const float hstep = 0.125f;
    const float d0 = (float)(rbase + c16) * hstep;
    const float d1 = (float)(rbase + 16 + c16) * hstep;

    const float BAND = 1.05f;
    float lo = (float)rbase * hstep, hi = (float)(rbase + 31) * hstep;
    int L = max(0, (int)floorf(((lo - BAND - 0.1f) * INVSTEP - 31.f) * 0.03125f));
    int H = min(9, (int)floorf(((hi + BAND - 0.1f) * INVSTEP) * 0.03125f));

    f32x4 acc[2][8];
#pragma unroll
    for (int a = 0; a < 2; ++a)
#pragma unroll
        for (int b = 0; b < 8; ++b) acc[a][b] = (f32x4){0.f, 0.f, 0.f, 0.f};

    for (int kc = L; kc <= H; ++kc) {
        int k0 = kc * 32 + g * 8;
        short8 bfr[8];
#pragma unroll
        for (int nb = 0; nb < 8; ++nb)
            bfr[nb] = load_bfrag_f32_g(Wcf1, k0, nb * 16 + c16, NRBF);
        const float cg = 0.1f + (float)k0 * STEPC;
        short8 a0 = rbf_row8(d0, cg);
        short8 a1 = rbf_row8(d1, cg);
#pragma unroll
        for (int nb = 0; nb < 8; ++nb) {
            acc[0][nb] = __builtin_amdgcn_mfma_f32_16x16x32_bf16(a0, bfr[nb], acc[0][nb], 0, 0, 0);
            acc[1][nb] = __builtin_amdgcn_mfma_f32_16x16x32_bf16(a1, bfr[nb], acc[1][nb], 0, 0, 0);
        }
    }

#pragma unroll
    for (int mr = 0; mr < 2; ++mr)
#pragma unroll
        for (int nb = 0; nb < 8; ++nb)
#pragma unroll
            for (int q = 0; q < 4; ++q) {
                int row = w * 32 + mr * 16 + 4 * g + q;
                A2[row][nb * 16 + c16] = f2bf_rhu(ssp_poly(acc[mr][nb][q]));
            }

    f32x4 acc2[2][8];
#pragma unroll
    for (int a = 0; a < 2; ++a)
#pragma unroll
        for (int b = 0; b < 8; ++b) acc2[a][b] = (f32x4){0.f, 0.f, 0.f, 0.f};

#pragma unroll
    for (int kc = 0; kc < 4; ++kc) {
        short8 a0 = *(const short8*)&A2[w * 32 + c16][kc * 32 + g * 8];
        short8 a1 = *(const short8*)&A2[w * 32 + 16 + c16][kc * 32 + g * 8];
#pragma unroll
        for (int nb = 0; nb < 8; ++nb) {
            short8 b = load_bfrag_f32(Wcf2, kc * 32 + g * 8, nb * 16 + c16);
            acc2[0][nb] = __builtin_amdgcn_mfma_f32_16x16x32_bf16(a0, b, acc2[0][nb], 0, 0, 0);
            acc2[1][nb] = __builtin_amdgcn_mfma_f32_16x16x32_bf16(a1, b, acc2[1][nb], 0, 0, 0);
        }
    }

#pragma unroll
    for (int mr = 0; mr < 2; ++mr)
#pragma unroll
        for (int q = 0; q < 4; ++q) {
            int rr = rbase + mr * 16 + 4 * g + q;
#pragma unroll
            for (int p2 = 0; p2 < 4; ++p2) {
                float F0 = ssp_poly(acc2[mr][2 * p2][q]);
                float F1 = ssp_poly(acc2[mr][2 * p2 + 1][q]);
                T[rr * 64 + c16 * 4 + p2] =
                    ((unsigned int)f2bf_rne(F1) << 16) | f2bf_rne(F0);
            }
        }
}

// Fused cfconv + post. 512 threads / 8 waves / 16 atoms per block, grid 625.
// Phase 1 (conv): table (64KB) staged once; wave w handles atoms w and w+8
// jammed; edge loop processed in batches of 8 with all loads (16 global preP
// + 32 LDS) issued before the compute uses them -> deep MLP. Lane owns column
// pair (c0 = 32*(lane&3)+(lane>>2), c0+16), accumulates the full 32-edge sum.
// Phase 2 (post): out = ssp(Aconv @ W1 + b1) @ W2 + b2 + resid; 8 waves
// col-split (wave = 16 rows x 16 cols); Amid reuses the dead table LDS.
__global__ __launch_bounds__(512, 2) void conv_post(
    const float* __restrict__ xyz, const int* __restrict__ src,
    const float* __restrict__ mask, const unsigned int* __restrict__ preP,
    const unsigned int* __restrict__ T, const unsigned short* __restrict__ w1,
    const float* __restrict__ b1, const unsigned short* __restrict__ w2,
    const float* __restrict__ b2, const float* __restrict__ resid,
    float* __restrict__ Y) {
    __shared__ unsigned int Tl[TROWS * 64];       // 64 KB (reused as Amid in phase 2)
    __shared__ unsigned short Aconv[16][132];     // 4.2 KB

    const int tid = threadIdx.x;
    const int w = tid >> 6;
    const int lane = tid & 63;
    const int l5 = lane & 31;
    const int c16 = lane & 15;
    const int g = lane >> 4;

    // stage table: 8 waves x 8 issues x 1KB
#pragma unroll
    for (int it = 0; it < 8; ++it) {
        const unsigned int* gp = T + w * 2048 + it * 256 + lane * 4;
        gload_lds16(gp, &Tl[w * 2048 + it * 256]);
    }

    // ---- phase 1 setup: two atoms per wave ----
    const int iA = blockIdx.x * 16 + w;
    const int iB = iA + 8;

    int svA = src[iA * KNB + l5];
    int svB = src[iB * KNB + l5];
    float mvA = mask[iA * KNB + l5];
    float mvB = mask[iB * KNB + l5];
    float dxA = xyz[3 * svA]     - xyz[3 * iA];
    float dyA = xyz[3 * svA + 1] - xyz[3 * iA + 1];
    float dzA = xyz[3 * svA + 2] - xyz[3 * iA + 2];
    float dxB = xyz[3 * svB]     - xyz[3 * iB];
    float dyB = xyz[3 * svB + 1] - xyz[3 * iB + 1];
    float dzB = xyz[3 * svB + 2] - xyz[3 * iB + 2];
    float dA = sqrtf(dxA * dxA + dyA * dyA + dzA * dzA);
    float dB = sqrtf(dxB * dxB + dyB * dyB + dzB * dzB);
    dA = (mvA > 0.f) ? dA : 1e9f;
    dB = (mvB > 0.f) ? dB : 1e9f;
    float tA = fminf(dA * 8.0f, (float)(TROWS - 2) + 0.999f);
    float tB = fminf(dB * 8.0f, (float)(TROWS - 2) + 0.999f);
    float fiA = floorf(tA), fiB = floorf(tB);
    float frA = tA - fiA,  frB = tB - fiB;
    int iiA = (int)fiA, iiB = (int)fiB;

    __syncthreads();   // table staged (drains gload_lds)

    // ---- jammed + 8-batched 32-edge loop over both atoms ----
    float a00 = 0.f, a01 = 0.f, a10 = 0.f, a11 = 0.f;
#pragma unroll
    for (int eb = 0; eb < KNB; eb += 8) {
        unsigned int tA0[8], tB0[8], tA1[8], tB1[8], q0[8], q1[8];
        float fr0[8], fr1[8];
#pragma unroll
        for (int j = 0; j < 8; ++j) {
            const int e = eb + j;
            int ie0 = __builtin_amdgcn_readlane(iiA, e);
            int se0 = __builtin_amdgcn_readlane(svA, e);
            fr0[j] = __uint_as_float((unsigned int)__builtin_amdgcn_readlane(
                         (int)__float_as_uint(frA), e));
            int ie1 = __builtin_amdgcn_readlane(iiB, e);
            int se1 = __builtin_amdgcn_readlane(svB, e);
            fr1[j] = __uint_as_float((unsigned int)__builtin_amdgcn_readlane(
                         (int)__float_as_uint(frB), e));
            q0[j] = preP[se0 * 64 + lane];
            q1[j] = preP[se1 * 64 + lane];
            tA0[j] = Tl[ie0 * 64 + lane];
            tB0[j] = Tl[ie0 * 64 + 64 + lane];
            tA1[j] = Tl[ie1 * 64 + lane];
            tB1[j] = Tl[ie1 * 64 + 64 + lane];
        }
#pragma unroll
        for (int j = 0; j < 8; ++j) {
            float A00 = __uint_as_float(tA0[j] << 16);
            float A01 = __uint_as_float(tA0[j] & 0xffff0000u);
            float B00 = __uint_as_float(tB0[j] << 16);
            float B01 = __uint_as_float(tB0[j] & 0xffff0000u);
            float f00 = fmaf(fr0[j], B00 - A00, A00);
            float f01 = fmaf(fr0[j], B01 - A01, A01);
            a00 = fmaf(f00, __uint_as_float(q0[j] << 16), a00);
            a01 = fmaf(f01, __uint_as_float(q0[j] & 0xffff0000u), a01);
            float A10 = __uint_as_float(tA1[j] << 16);
            float A11 = __uint_as_float(tA1[j] & 0xffff0000u);
            float B10 = __uint_as_float(tB1[j] << 16);
            float B11 = __uint_as_float(tB1[j] & 0xffff0000u);
            float f10 = fmaf(fr1[j], B10 - A10, A10);
            float f11 = fmaf(fr1[j], B11 - A11, A11);
            a10 = fmaf(f10, __uint_as_float(q1[j] << 16), a10);
            a11 = fmaf(f11, __uint_as_float(q1[j] & 0xffff0000u), a11);
        }
    }
    // each lane holds the complete 32-edge sums for its column pair
    {
        int c0 = 32 * (lane & 3) + (lane >> 2);
        Aconv[w][c0]          = f2bf_rhu(a00);
        Aconv[w][c0 + 16]     = f2bf_rhu(a01);
        Aconv[w + 8][c0]      = f2bf_rhu(a10);
        Aconv[w + 8][c0 + 16] = f2bf_rhu(a11);
    }
    __syncthreads();   // Aconv complete; table LDS now dead

    // ---- phase 2: post. wave w: 16 rows x cols [w*16, w*16+16) ----
    unsigned short* Amid = (unsigned short*)Tl;   // [16][132] reuse
    const int r0 = blockIdx.x * 16;

    f32x4 acc = (f32x4){0.f, 0.f, 0.f, 0.f};
#pragma unroll
    for (int kc = 0; kc < 4; ++kc) {
        short8 a0 = *(const short8*)&Aconv[c16][kc * 32 + g * 8];
        const unsigned short* wb = w1 + (kc * 4 + g) * 1024;
        short8 b = *(const short8*)(wb + (w * 16 + c16) * 8);
        acc = __builtin_amdgcn_mfma_f32_16x16x32_bf16(a0, b, acc, 0, 0, 0);
    }
    {
        float bv = b1[w * 16 + c16];
#pragma unroll
        for (int q = 0; q < 4; ++q)
            Amid[(4 * g + q) * 132 + w * 16 + c16] =
                f2bf_rhu(ssp_fast(acc[q] + bv));
    }
    __syncthreads();

    f32x4 acc2 = (f32x4){0.f, 0.f, 0.f, 0.f};
#pragma unroll
    for (int kc = 0; kc < 4; ++kc) {
        short8 a0 = *(const short8*)&Amid[c16 * 132 + kc * 32 + g * 8];
        const unsigned short* wb = w2 + (kc * 4 + g) * 1024;
        short8 b = *(const short8*)(wb + (w * 16 + c16) * 8);
        acc2 = __builtin_amdgcn_mfma_f32_16x16x32_bf16(a0, b, acc2, 0, 0, 0);
    }
    {
        float bv2 = b2[w * 16 + c16];
#pragma unroll
        for (int q = 0; q < 4; ++q) {
            int o = (r0 + 4 * g + q) * FD + w * 16 + c16;
            Y[o] = acc2[q] + bv2 + resid[o];
        }
    }
}

extern "C" void kernel_launch(void* const* d_in, const int* in_sizes, int n_in,
                              void* d_out, int out_size, void* d_ws, size_t ws_size,
                              hipStream_t stream) {
    const float* xyz     = (const float*)d_in[0];
    const float* atomic  = (const float*)d_in[1];
    const float* mask    = (const float*)d_in[2];
    const int*   src     = (const int*)d_in[3];
    const float* W_pre   = (const float*)d_in[4];
    const float* b_pre   = (const float*)d_in[5];
    const float* W_cf1   = (const float*)d_in[6];
    const float* W_cf2   = (const float*)d_in[7];
    const float* W_post1 = (const float*)d_in[8];
    const float* b_post1 = (const float*)d_in[9];
    const float* W_post2 = (const float*)d_in[10];
    const float* b_post2 = (const float*)d_in[11];
    float* out = (float*)d_out;

    unsigned int*   preP = (unsigned int*)d_ws;                       // 2.56 MB
    unsigned int*   T    = (unsigned int*)((char*)d_ws + 2560000);    // 64 KB
    unsigned short* wp   = (unsigned short*)((char*)d_ws + 2625536);  // 64 KB

    pre_table_pack<<<317, 256, 0, stream>>>(atomic, W_pre, b_pre, preP,
                                            W_cf1, W_cf2, T, W_post1, W_post2, wp);
    conv_post<<<625, 512, 0, stream>>>(xyz, src, mask, preP, T,
                                       wp, b_post1, wp + 16384, b_post2, atomic, out);
}

// Round 15
// 39.344 us; speedup vs baseline: 2.0573x; 2.0573x over previous
//
#include <hip/hip_runtime.h>

#define NATOMS 10000
#define KNB 32
#define FD 128
#define NRBF 300
#define STEPC (30.0f / 299.0f)      // linspace(0.1,30.1,300) step
#define INVSTEP (299.0f / 30.0f)
#define TROWS 256                   // filter table rows, d in [0,32), h = 1/8

typedef short short8 __attribute__((ext_vector_type(8)));
typedef float f32x4 __attribute__((ext_vector_type(4)));
typedef unsigned int u32x4 __attribute__((ext_vector_type(4)));

__device__ __forceinline__ unsigned short f2bf_rne(float f) {
    unsigned int u = __float_as_uint(f);
    u = (u + 0x7fffu + ((u >> 16) & 1u)) >> 16;
    return (unsigned short)u;
}

// pack two floats -> one u32 of 2 bf16 (round-half-up), lo in bits[15:0]
__device__ __forceinline__ unsigned int pack_bf2(float hi, float lo) {
    return __builtin_amdgcn_perm(__float_as_uint(hi) + 0x8000u,
                                 __float_as_uint(lo) + 0x8000u, 0x07060302u);
}

__device__ __forceinline__ unsigned short f2bf_rhu(float f) {
    return (unsigned short)((__float_as_uint(f) + 0x8000u) >> 16);
}

// exact-ish shifted softplus (2 trans) — unbounded input
__device__ __forceinline__ float ssp_fast(float x) {
    float t = __builtin_amdgcn_exp2f(x * 1.44269504f);
    float l = __builtin_amdgcn_logf(1.0f + t);
    return 0.69314718056f * (l - 1.0f);
}

// even-series shifted softplus, valid |x| <= ~2.5, NO transcendentals.
__device__ __forceinline__ float ssp_poly(float x) {
    float u = x * x;
    float p = fmaf(u, 2.1356923e-6f, -2.6351976e-5f);
    p = fmaf(u, p, 3.2552083e-4f);
    p = fmaf(u, p, -5.2083333e-3f);
    p = fmaf(u, p, 0.125f);
    return fmaf(0.5f, x, u * p);
}

// async global->LDS, 16B per lane; lds dest = wave-uniform base + lane*16
__device__ __forceinline__ void gload_lds16(const void* g, void* l) {
    __builtin_amdgcn_global_load_lds(
        (const __attribute__((address_space(1))) unsigned int*)g,
        (__attribute__((address_space(3))) unsigned int*)l, 16, 0, 0);
}

// 8 consecutive RBF values for distance d, packed bf16 (recurrence, 2 exp2)
__device__ __forceinline__ short8 rbf_row8(float d, float cg) {
    float t = d - cg;
    t = fminf(3.5f, fmaxf(-3.5f, t));
    float r = __builtin_amdgcn_exp2f(-14.4269504f * t * t);
    float q = __builtin_amdgcn_exp2f((28.8539008f * STEPC) * t
                                     - (14.4269504f * STEPC * STEPC));
    const float QRATIO = 0.81763172f;                 // 2^(-28.8539008*STEPC^2)
    u32x4 p;
#pragma unroll
    for (int jj = 0; jj < 4; ++jj) {
        float v0 = r; r *= q; q *= QRATIO;
        float v1 = r; r *= q; q *= QRATIO;
        p[jj] = pack_bf2(v1, v0);
    }
    return __builtin_bit_cast(short8, p);
}

// Pack W_cf1 (300x128) -> bf16 [10][4][128][8]; then Wpre/Wcf2/Wpost1/Wpost2
// (128x128 each) -> bf16 [4][4][128][8] at w4p + sel*16384.
__global__ __launch_bounds__(256) void prep_pack(
    const float* __restrict__ Wcf1, const float* __restrict__ Wpre,
    const float* __restrict__ Wcf2, const float* __restrict__ Wpost1,
    const float* __restrict__ Wpost2, unsigned short* __restrict__ w1p,
    unsigned short* __restrict__ w4p) {
    int idx = blockIdx.x * 256 + threadIdx.x;
    if (idx < 40960) {
        int j = idx & 7, c = (idx >> 3) & 127, g = (idx >> 10) & 3, kc = idx >> 12;
        int k = kc * 32 + g * 8 + j;
        float v = (k < NRBF) ? Wcf1[k * FD + c] : 0.f;
        w1p[idx] = f2bf_rne(v);
    } else if (idx < 40960 + 65536) {
        int t = idx - 40960;
        int sel = t >> 14;
        int t2 = t & 16383;
        int j = t2 & 7, c = (t2 >> 3) & 127, g = (t2 >> 10) & 3, kc = t2 >> 12;
        int k = kc * 32 + g * 8 + j;
        const float* W = (sel == 0) ? Wpre : (sel == 1) ? Wcf2 : (sel == 2) ? Wpost1 : Wpost2;
        w4p[t] = f2bf_rne(W[k * FD + c]);
    }
}

// Role-split: blocks [0,157) compute pre (bf16 pair-swizzled preP); blocks
// [157,159) build the 256-row filter table T (d = r/8, F = ssp(ssp(rbf@W1)@W2),
// entry (r, j) u32 = bf16 pair cols (32*(j&3)+(j>>2), +16), j = c16*4+p2).
__global__ __launch_bounds__(256) void pre_and_table(
    const float* __restrict__ X, const unsigned short* __restrict__ Wp,
    const float* __restrict__ bias, unsigned int* __restrict__ preP,
    const unsigned short* __restrict__ w1p, const unsigned short* __restrict__ w2p,
    unsigned int* __restrict__ T) {
    __shared__ unsigned short A2[128][132];   // table role only
    const int tid = threadIdx.x;
    const int w = tid >> 6, lane = tid & 63, g = lane >> 4, c16 = lane & 15;

    if (blockIdx.x < 157) {
        const int r0 = blockIdx.x * 64 + w * 16;
        f32x4 acc[8];
#pragma unroll
        for (int b = 0; b < 8; ++b) acc[b] = (f32x4){0.f, 0.f, 0.f, 0.f};
        int row = r0 + c16;
        if (row >= NATOMS) row = 0;
#pragma unroll
        for (int kc = 0; kc < 4; ++kc) {
            const float* p0 = X + (size_t)row * FD + kc * 32 + g * 8;
            float4 xa = *(const float4*)p0, xb = *(const float4*)(p0 + 4);
            u32x4 pa;
            pa[0] = pack_bf2(xa.y, xa.x); pa[1] = pack_bf2(xa.w, xa.z);
            pa[2] = pack_bf2(xb.y, xb.x); pa[3] = pack_bf2(xb.w, xb.z);
            short8 a0 = __builtin_bit_cast(short8, pa);
            const unsigned short* wb = Wp + (kc * 4 + g) * 1024 + c16 * 8;
#pragma unroll
            for (int nb = 0; nb < 8; ++nb) {
                short8 b = *(const short8*)(wb + nb * 128);
                acc[nb] = __builtin_amdgcn_mfma_f32_16x16x32_bf16(a0, b, acc[nb], 0, 0, 0);
            }
        }
        float bv[8];
#pragma unroll
        for (int nb = 0; nb < 8; ++nb) bv[nb] = bias[nb * 16 + c16];
#pragma unroll
        for (int q = 0; q < 4; ++q) {
            int orow = r0 + 4 * g + q;
            if (orow < NATOMS) {
#pragma unroll
                for (int p2 = 0; p2 < 4; ++p2) {
                    float v0 = acc[2 * p2][q] + bv[2 * p2];
                    float v1 = acc[2 * p2 + 1][q] + bv[2 * p2 + 1];
                    preP[orow * 64 + c16 * 4 + p2] = pack_bf2(v1, v0);
                }
            }
        }
        return;
    }

    // ---- table role: 32 rows/wave, 128 rows/block, d = r/8 ----
    const int rbase = (int)(blockIdx.x - 157) * 128 + w * 32;
    const float hstep = 0.125f;
    const float d0 = (float)(rbase + c16) * hstep;
    const float d1 = (float)(rbase + 16 + c16) * hstep;

    const float BAND = 1.05f;
    float lo = (float)rbase * hstep, hi = (float)(rbase + 31) * hstep;
    int L = max(0, (int)floorf(((lo - BAND - 0.1f) * INVSTEP - 31.f) * 0.03125f));
    int H = min(9, (int)floorf(((hi + BAND - 0.1f) * INVSTEP) * 0.03125f));

    f32x4 acc[2][8];
#pragma unroll
    for (int a = 0; a < 2; ++a)
#pragma unroll
        for (int b = 0; b < 8; ++b) acc[a][b] = (f32x4){0.f, 0.f, 0.f, 0.f};

    for (int kc = L; kc <= H; ++kc) {
        const unsigned short* wb = w1p + kc * 4096 + g * 1024 + c16 * 8;
        short8 bfr[8];
#pragma unroll
        for (int nb = 0; nb < 8; ++nb) bfr[nb] = *(const short8*)(wb + nb * 128);
        const float cg = 0.1f + (float)(kc * 32 + g * 8) * STEPC;
        short8 a0 = rbf_row8(d0, cg);
        short8 a1 = rbf_row8(d1, cg);
#pragma unroll
        for (int nb = 0; nb < 8; ++nb) {
            acc[0][nb] = __builtin_amdgcn_mfma_f32_16x16x32_bf16(a0, bfr[nb], acc[0][nb], 0, 0, 0);
            acc[1][nb] = __builtin_amdgcn_mfma_f32_16x16x32_bf16(a1, bfr[nb], acc[1][nb], 0, 0, 0);
        }
    }

#pragma unroll
    for (int mr = 0; mr < 2; ++mr)
#pragma unroll
        for (int nb = 0; nb < 8; ++nb)
#pragma unroll
            for (int q = 0; q < 4; ++q) {
                int row = w * 32 + mr * 16 + 4 * g + q;
                A2[row][nb * 16 + c16] = f2bf_rhu(ssp_poly(acc[mr][nb][q]));
            }

    f32x4 acc2[2][8];
#pragma unroll
    for (int a = 0; a < 2; ++a)
#pragma unroll
        for (int b = 0; b < 8; ++b) acc2[a][b] = (f32x4){0.f, 0.f, 0.f, 0.f};

#pragma unroll
    for (int kc = 0; kc < 4; ++kc) {
        short8 a0 = *(const short8*)&A2[w * 32 + c16][kc * 32 + g * 8];
        short8 a1 = *(const short8*)&A2[w * 32 + 16 + c16][kc * 32 + g * 8];
        const unsigned short* wb = w2p + (kc * 4 + g) * 1024 + c16 * 8;
#pragma unroll
        for (int nb = 0; nb < 8; ++nb) {
            short8 b = *(const short8*)(wb + nb * 128);
            acc2[0][nb] = __builtin_amdgcn_mfma_f32_16x16x32_bf16(a0, b, acc2[0][nb], 0, 0, 0);
            acc2[1][nb] = __builtin_amdgcn_mfma_f32_16x16x32_bf16(a1, b, acc2[1][nb], 0, 0, 0);
        }
    }

#pragma unroll
    for (int mr = 0; mr < 2; ++mr)
#pragma unroll
        for (int q = 0; q < 4; ++q) {
            int r = rbase + mr * 16 + 4 * g + q;
#pragma unroll
            for (int p2 = 0; p2 < 4; ++p2) {
                float F0 = ssp_poly(acc2[mr][2 * p2][q]);
                float F1 = ssp_poly(acc2[mr][2 * p2 + 1][q]);
                T[r * 64 + c16 * 4 + p2] =
                    ((unsigned int)f2bf_rne(F1) << 16) | f2bf_rne(F0);
            }
        }
}

// Fused cfconv + post. 512 threads / 8 waves / 16 atoms per block, grid 625.
// Phase 1 (conv): table (64KB) staged once; wave w handles atoms w and w+8
// jammed; edge loop in batches of 8: hoist readlane scalars, issue all 16
// global preP + 32 LDS loads, then consume -> deep memory-level parallelism.
// Lane owns column pair (c0 = 32*(lane&3)+(lane>>2), c0+16).
// Phase 2 (post): out = ssp(Aconv @ W1 + b1) @ W2 + b2 + resid; 8 waves
// col-split (wave = 16 rows x 16 cols); Amid reuses the dead table LDS.
__global__ __launch_bounds__(512, 2) void conv_post(
    const float* __restrict__ xyz, const int* __restrict__ src,
    const float* __restrict__ mask, const unsigned int* __restrict__ preP,
    const unsigned int* __restrict__ T, const unsigned short* __restrict__ w1,
    const float* __restrict__ b1, const unsigned short* __restrict__ w2,
    const float* __restrict__ b2, const float* __restrict__ resid,
    float* __restrict__ Y) {
    __shared__ unsigned int Tl[TROWS * 64];       // 64 KB (reused as Amid in phase 2)
    __shared__ unsigned short Aconv[16][132];     // 4.2 KB

    const int tid = threadIdx.x;
    const int w = tid >> 6;
    const int lane = tid & 63;
    const int l5 = lane & 31;
    const int c16 = lane & 15;
    const int g = lane >> 4;

    // stage table: 8 waves x 8 issues x 1KB
#pragma unroll
    for (int it = 0; it < 8; ++it) {
        const unsigned int* gp = T + w * 2048 + it * 256 + lane * 4;
        gload_lds16(gp, &Tl[w * 2048 + it * 256]);
    }

    // ---- phase 1 setup: two atoms per wave ----
    const int iA = blockIdx.x * 16 + w;
    const int iB = iA + 8;

    int svA = src[iA * KNB + l5];
    int svB = src[iB * KNB + l5];
    float mvA = mask[iA * KNB + l5];
    float mvB = mask[iB * KNB + l5];
    float dxA = xyz[3 * svA]     - xyz[3 * iA];
    float dyA = xyz[3 * svA + 1] - xyz[3 * iA + 1];
    float dzA = xyz[3 * svA + 2] - xyz[3 * iA + 2];
    float dxB = xyz[3 * svB]     - xyz[3 * iB];
    float dyB = xyz[3 * svB + 1] - xyz[3 * iB + 1];
    float dzB = xyz[3 * svB + 2] - xyz[3 * iB + 2];
    float dA = sqrtf(dxA * dxA + dyA * dyA + dzA * dzA);
    float dB = sqrtf(dxB * dxB + dyB * dyB + dzB * dzB);
    dA = (mvA > 0.f) ? dA : 1e9f;
    dB = (mvB > 0.f) ? dB : 1e9f;
    float tA = fminf(dA * 8.0f, (float)(TROWS - 2) + 0.999f);
    float tB = fminf(dB * 8.0f, (float)(TROWS - 2) + 0.999f);
    float fiA = floorf(tA), fiB = floorf(tB);
    float frA = tA - fiA,  frB = tB - fiB;
    int iiA = (int)fiA, iiB = (int)fiB;

    __syncthreads();   // table staged (drains gload_lds)

    // ---- jammed + 8-batched 32-edge loop over both atoms ----
    float a00 = 0.f, a01 = 0.f, a10 = 0.f, a11 = 0.f;
#pragma unroll
    for (int eb = 0; eb < KNB; eb += 8) {
        unsigned int tA0[8], tB0[8], tA1[8], tB1[8], q0[8], q1[8];
        float fr0[8], fr1[8];
#pragma unroll
        for (int j = 0; j < 8; ++j) {
            const int e = eb + j;
            int ie0 = __builtin_amdgcn_readlane(iiA, e);
            int se0 = __builtin_amdgcn_readlane(svA, e);
            fr0[j] = __uint_as_float((unsigned int)__builtin_amdgcn_readlane(
                         (int)__float_as_uint(frA), e));
            int ie1 = __builtin_amdgcn_readlane(iiB, e);
            int se1 = __builtin_amdgcn_readlane(svB, e);
            fr1[j] = __uint_as_float((unsigned int)__builtin_amdgcn_readlane(
                         (int)__float_as_uint(frB), e));
            q0[j] = preP[se0 * 64 + lane];
            q1[j] = preP[se1 * 64 + lane];
            tA0[j] = Tl[ie0 * 64 + lane];
            tB0[j] = Tl[ie0 * 64 + 64 + lane];
            tA1[j] = Tl[ie1 * 64 + lane];
            tB1[j] = Tl[ie1 * 64 + 64 + lane];
        }
#pragma unroll
        for (int j = 0; j < 8; ++j) {
            float A00 = __uint_as_float(tA0[j] << 16);
            float A01 = __uint_as_float(tA0[j] & 0xffff0000u);
            float B00 = __uint_as_float(tB0[j] << 16);
            float B01 = __uint_as_float(tB0[j] & 0xffff0000u);
            float f00 = fmaf(fr0[j], B00 - A00, A00);
            float f01 = fmaf(fr0[j], B01 - A01, A01);
            a00 = fmaf(f00, __uint_as_float(q0[j] << 16), a00);
            a01 = fmaf(f01, __uint_as_float(q0[j] & 0xffff0000u), a01);
            float A10 = __uint_as_float(tA1[j] << 16);
            float A11 = __uint_as_float(tA1[j] & 0xffff0000u);
            float B10 = __uint_as_float(tB1[j] << 16);
            float B11 = __uint_as_float(tB1[j] & 0xffff0000u);
            float f10 = fmaf(fr1[j], B10 - A10, A10);
            float f11 = fmaf(fr1[j], B11 - A11, A11);
            a10 = fmaf(f10, __uint_as_float(q1[j] << 16), a10);
            a11 = fmaf(f11, __uint_as_float(q1[j] & 0xffff0000u), a11);
        }
    }
    // each lane holds the complete 32-edge sums for its column pair
    {
        int c0 = 32 * (lane & 3) + (lane >> 2);
        Aconv[w][c0]          = f2bf_rhu(a00);
        Aconv[w][c0 + 16]     = f2bf_rhu(a01);
        Aconv[w + 8][c0]      = f2bf_rhu(a10);
        Aconv[w + 8][c0 + 16] = f2bf_rhu(a11);
    }
    __syncthreads();   // Aconv complete; table LDS now dead

    // ---- phase 2: post. wave w: 16 rows x cols [w*16, w*16+16) ----
    unsigned short* Amid = (unsigned short*)Tl;   // [16][132] reuse
    const int r0 = blockIdx.x * 16;

    f32x4 acc = (f32x4){0.f, 0.f, 0.f, 0.f};
#pragma unroll
    for (int kc = 0; kc < 4; ++kc) {
        short8 a0 = *(const short8*)&Aconv[c16][kc * 32 + g * 8];
        const unsigned short* wb = w1 + (kc * 4 + g) * 1024;
        short8 b = *(const short8*)(wb + (w * 16 + c16) * 8);
        acc = __builtin_amdgcn_mfma_f32_16x16x32_bf16(a0, b, acc, 0, 0, 0);
    }
    {
        float bv = b1[w * 16 + c16];
#pragma unroll
        for (int q = 0; q < 4; ++q)
            Amid[(4 * g + q) * 132 + w * 16 + c16] =
                f2bf_rhu(ssp_fast(acc[q] + bv));
    }
    __syncthreads();

    f32x4 acc2 = (f32x4){0.f, 0.f, 0.f, 0.f};
#pragma unroll
    for (int kc = 0; kc < 4; ++kc) {
        short8 a0 = *(const short8*)&Amid[c16 * 132 + kc * 32 + g * 8];
        const unsigned short* wb = w2 + (kc * 4 + g) * 1024;
        short8 b = *(const short8*)(wb + (w * 16 + c16) * 8);
        acc2 = __builtin_amdgcn_mfma_f32_16x16x32_bf16(a0, b, acc2, 0, 0, 0);
    }
    {
        float bv2 = b2[w * 16 + c16];
#pragma unroll
        for (int q = 0; q < 4; ++q) {
            int o = (r0 + 4 * g + q) * FD + w * 16 + c16;
            Y[o] = acc2[q] + bv2 + resid[o];
        }
    }
}

extern "C" void kernel_launch(void* const* d_in, const int* in_sizes, int n_in,
                              void* d_out, int out_size, void* d_ws, size_t ws_size,
                              hipStream_t stream) {
    const float* xyz     = (const float*)d_in[0];
    const float* atomic  = (const float*)d_in[1];
    const float* mask    = (const float*)d_in[2];
    const int*   src     = (const int*)d_in[3];
    const float* W_pre   = (const float*)d_in[4];
    const float* b_pre   = (const float*)d_in[5];
    const float* W_cf1   = (const float*)d_in[6];
    const float* W_cf2   = (const float*)d_in[7];
    const float* W_post1 = (const float*)d_in[8];
    const float* b_post1 = (const float*)d_in[9];
    const float* W_post2 = (const float*)d_in[10];
    const float* b_post2 = (const float*)d_in[11];
    float* out = (float*)d_out;

    unsigned int*   preP = (unsigned int*)d_ws;                       // 2.56 MB
    unsigned int*   T    = (unsigned int*)((char*)d_ws + 2560000);    // 64 KB
    unsigned short* w1p  = (unsigned short*)((char*)d_ws + 2625536);  // 80 KB
    unsigned short* w4p  = w1p + 40960;                               // 128 KB
    unsigned short* wpre   = w4p;
    unsigned short* wcf2   = w4p + 16384;
    unsigned short* wpost1 = w4p + 32768;
    unsigned short* wpost2 = w4p + 49152;

    prep_pack<<<416, 256, 0, stream>>>(W_cf1, W_pre, W_cf2, W_post1, W_post2, w1p, w4p);
    pre_and_table<<<159, 256, 0, stream>>>(atomic, wpre, b_pre, preP, w1p, wcf2, T);
    conv_post<<<625, 512, 0, stream>>>(xyz, src, mask, preP, T,
                                       wpost1, b_post1, wpost2, b_post2, atomic, out);
}